// Round 7
// baseline (303.710 us; speedup 1.0000x reference)
//
#include <hip/hip_runtime.h>
#include <math.h>

#define DIM 192
#define OD  191          // output domain per axis (191^3 outputs)
#define PLN 36864        // 192^2
#define VOLX 7077888     // 192^3
#define TW 32            // 2 voxels per thread in w
#define TH 16
#define NBW 6            // ceil(191/32)
#define NBH 12           // ceil(191/16)
#define CD  8
#define NCH 24           // 24*8 = 192 >= 191

#define RH 19            // raw halo rows   (h0-1 .. h0+17)
#define RW 35            // raw halo cols   (w0-1 .. w0+33)
#define NS (RH*RW)       // 665 staging points
#define DH 18            // diff rows
#define DW 34            // diff cols
#define SBW 34           // sB row stride

typedef _Float16 h2v __attribute__((ext_vector_type(2)));
typedef _Float16 h4  __attribute__((ext_vector_type(4)));
typedef _Float16 h8  __attribute__((ext_vector_type(8)));
typedef unsigned int u2v __attribute__((ext_vector_type(2)));

static __device__ __forceinline__ h4 habs4(h4 v) {
    u2v u = __builtin_bit_cast(u2v, v);
    u &= 0x7FFF7FFFu;
    return __builtin_bit_cast(h4, u);
}

// Fused: diff -> 3x3x3 box mean -> neo-hookean energy -> mean reduction.
// LDS = 17.9 KB (ONE raw plane + single diff buffer) => 8 blocks/CU, 32 waves
// (occupancy cap). Next raw plane carried in registers (D-diff uses regs
// directly); prefetch issued one full plane ahead of use.
__global__ __launch_bounds__(256, 8)
void nh_fused_kernel(const float* __restrict__ P, float* __restrict__ out) {
    const int tid = threadIdx.x;
    const int tx = tid & 15, ty = tid >> 4;
    const int w0 = blockIdx.x * TW, h0 = blockIdx.y * TH;
    const int ds = blockIdx.z * CD;
    const int de = min(ds + CD, OD);
    const int lastP = min(de + 1, DIM - 1);   // last raw plane index needed

    __shared__ h4  sraw[RH][RW];      // raw f16 {c0,c1,c2,0}; ONE plane
    __shared__ h8  sA[DH][RW];        // {H0,H1,H2,W0, D0,D1,D2,W1}
    __shared__ h2v sB[DH][SBW];       // {W2,0}
    __shared__ float wsum[4];

    const int oh = h0 + ty, ow0 = w0 + 2 * tx;
    const bool v0 = (oh < OD) && (ow0 < OD);
    const bool v1 = (oh < OD) && (ow0 + 1 < OD);

    // ---- unified staging/diff descriptors (665 pts, <=3 per thread) ----
    int  sL[3], sOff[3], sBl[3];
    bool sAct[3], sMask[3], sInD[3], sZero[3];
    #pragma unroll
    for (int i = 0; i < 3; ++i) {
        int l = tid + 256 * i;
        sAct[i] = (l < NS);
        l = min(l, NS - 1);
        const int sh = l / RW, sw = l - sh * RW;
        const int hp = h0 - 1 + sh, wp = w0 - 1 + sw;
        sMask[i] = (hp >= 0) && (hp < DIM) && (wp >= 0) && (wp < DIM);
        sOff[i]  = min(max(hp, 0), DIM - 1) * DIM + min(max(wp, 0), DIM - 1);
        sL[i]    = l;
        sInD[i]  = (sh < DH) && (sw < DW);
        sZero[i] = (hp < 0) || (hp >= OD) || (wp < 0) || (wp >= OD);
        sBl[i]   = sh * SBW + sw;
    }

    // in-flight prefetch registers (one raw plane, 3 channels, 3 items)
    float px[3][3];
    #pragma unroll
    for (int i = 0; i < 3; ++i) { px[i][0] = px[i][1] = px[i][2] = 0.f; }

    auto issue = [&](int q) {
        #pragma unroll
        for (int i = 0; i < 3; ++i) {
            if (sAct[i]) {
                const float* b = P + (size_t)q * PLN + sOff[i];
                px[i][0] = b[0]; px[i][1] = b[VOLX]; px[i][2] = b[2 * VOLX];
            }
        }
    };

    // ---- prologue: LDS raw <- plane ds-1 (if any); regs <- plane ds ----
    h4* const rawp = &sraw[0][0];
    if (ds >= 1) {
        issue(ds - 1);
        #pragma unroll
        for (int i = 0; i < 3; ++i) {
            if (sAct[i]) {
                rawp[sL[i]] = sMask[i] ? (h4){(_Float16)px[i][0], (_Float16)px[i][1],
                                              (_Float16)px[i][2], (_Float16)0.f}
                                       : (h4)0;
            }
        }
        issue(ds);
    } else {
        issue(0);   // loop's p=-1 iteration skips phase b; raw contents unread
    }
    __syncthreads();

    h8 rA0[2], rA1[2], rA2[2];
    _Float16 rB0[2], rB1[2], rB2[2];
    #pragma unroll
    for (int o = 0; o < 2; ++o) {
        rA0[o] = (h8)0; rA1[o] = (h8)0; rA2[o] = (h8)0;
        rB0[o] = (_Float16)0.f; rB1[o] = (_Float16)0.f; rB2[o] = (_Float16)0.f;
    }
    float acc = 0.f;

    for (int p = ds - 1; p <= de; ++p) {
        const bool pv = (p >= 0) && (p < OD);

        // convert regs (plane p+1) to f16 once; used by D-diff AND raw update
        h4 cvt[3];
        #pragma unroll
        for (int i = 0; i < 3; ++i) {
            cvt[i] = sMask[i] ? (h4){(_Float16)px[i][0], (_Float16)px[i][1],
                                     (_Float16)px[i][2], (_Float16)0.f}
                              : (h4)0;
        }

        // phase b: diffs of plane p (reads LDS raw plane p + cvt regs plane p+1)
        if (pv) {
            h8*  pA = &sA[0][0];
            h2v* pB = &sB[0][0];
            #pragma unroll
            for (int i = 0; i < 3; ++i) {
                if (sAct[i] && sInD[i]) {
                    const int li = sL[i];
                    const h4 c  = rawp[li];
                    h4 hd = habs4(rawp[li + RW] - c);   // H-diff
                    h4 wd = habs4(rawp[li + 1]  - c);   // W-diff
                    h4 dd = habs4(cvt[i]        - c);   // D-diff (regs)
                    if (sZero[i]) { hd = (h4)0; wd = (h4)0; dd = (h4)0; }
                    const h4 lo = __builtin_shufflevector(hd, wd, 0, 1, 2, 4);
                    const h4 hi = __builtin_shufflevector(dd, wd, 0, 1, 2, 5);
                    pA[li] = __builtin_shufflevector(lo, hi, 0, 1, 2, 3, 4, 5, 6, 7);
                    pB[sBl[i]] = (h2v){wd[2], (_Float16)0.f};
                }
            }
        }

        // launch next prefetch (plane p+2) — full plane of work before its use
        if (p + 2 <= lastP) issue(p + 2);
        __syncthreads();

        // phase c: 3x3 window sums for 2 outputs; rotate ring
        #pragma unroll
        for (int o = 0; o < 2; ++o) {
            rA0[o] = rA1[o]; rA1[o] = rA2[o];
            rB0[o] = rB1[o]; rB1[o] = rB2[o];
        }
        if (pv) {
            h8 s0 = (h8)0, s1 = (h8)0;
            _Float16 q0 = (_Float16)0.f, q1 = (_Float16)0.f;
            #pragma unroll
            for (int j = 0; j < 3; ++j) {
                const h8* rowA = &sA[ty + j][2 * tx];
                const h8 t0 = rowA[0], t1 = rowA[1], t2 = rowA[2], t3 = rowA[3];
                const h4* rowB = (const h4*)&sB[ty + j][2 * tx];
                const h4 u01 = rowB[0], u23 = rowB[1];   // {W2(c),0,W2(c+1),0} x2
                const h8 m = t1 + t2;
                s0 += t0 + m;
                s1 += t3 + m;
                const _Float16 mB = u01[2] + u23[0];
                q0 += u01[0] + mB;
                q1 += u23[2] + mB;
            }
            rA2[0] = s0; rA2[1] = s1; rB2[0] = q0; rB2[1] = q1;
        } else {
            rA2[0] = (h8)0; rA2[1] = (h8)0;
            rB2[0] = (_Float16)0.f; rB2[1] = (_Float16)0.f;
        }

        // emit output plane d = p-1 (wsums d-1,d,d+1 = rA0,rA1,rA2)
        const int d = p - 1;
        if (d >= ds) {
            #pragma unroll
            for (int o = 0; o < 2; ++o) {
                if (o == 0 ? v0 : v1) {
                    const h8 FA = rA0[o] + rA1[o] + rA2[o];
                    const float FBz = (float)(rB0[o] + rB1[o] + rB2[o]);
                    const float inv27 = 1.f / 27.f;
                    const float dydx = (float)FA[0] * inv27, dxdx = (float)FA[1] * inv27, dzdx = (float)FA[2] * inv27;
                    const float dydz = (float)FA[3] * inv27;                       // W0
                    const float dydy = (float)FA[4] * inv27, dxdy = (float)FA[5] * inv27, dzdy = (float)FA[6] * inv27;
                    const float dxdz = (float)FA[7] * inv27;                       // W1
                    const float dzdz = FBz * inv27;                                 // W2
                    const float a = dxdx + 1.f, e = dydy + 1.f, iN = dzdz + 1.f;
                    const float J = a * (e * iN - dydz * dzdy)
                                  - dxdy * (dydx * iN - dydz * dzdx)
                                  + dxdz * (dydx * dzdy - e * dzdx);
                    const float Tr = a * a + dxdy * dxdy + dxdz * dxdz
                                   + dydx * dydx + e * e + dydz * dydz
                                   + dzdx * dzdx + dzdy * dzdy + iN * iN;
                    const float stretch = Tr * __expf(1.f - J) - 3.f;
                    const float vol = (J - 1.f) * (J - 1.f);
                    // mu=1,lam=5 -> U = (1/12)*stretch + (15/31)*vol (verified R1-R6)
                    acc += 0.0833333358f * stretch + 0.4838709677f * vol;
                }
            }
        }

        // raw update: LDS raw <- plane p+1 (readers of plane p done at barrier)
        #pragma unroll
        for (int i = 0; i < 3; ++i) {
            if (sAct[i]) rawp[sL[i]] = cvt[i];
        }
        __syncthreads();
    }

    // mean scaling (191^3)
    acc *= (1.f / 6967871.f);

    // wave reduce (64 lanes), then block reduce, one atomic per block
    #pragma unroll
    for (int off = 32; off > 0; off >>= 1) acc += __shfl_down(acc, off, 64);
    if ((tid & 63) == 0) wsum[tid >> 6] = acc;
    __syncthreads();
    if (tid == 0) {
        atomicAdd(out, wsum[0] + wsum[1] + wsum[2] + wsum[3]);
    }
}

extern "C" void kernel_launch(void* const* d_in, const int* in_sizes, int n_in,
                              void* d_out, int out_size, void* d_ws, size_t ws_size,
                              hipStream_t stream) {
    const float* y_pred = (const float*)d_in[0];
    float* out = (float*)d_out;

    // d_out is poisoned 0xAA before every timed launch — zero it (graph-capturable).
    hipMemsetAsync(out, 0, sizeof(float), stream);

    dim3 grid(NBW, NBH, NCH);
    nh_fused_kernel<<<grid, 256, 0, stream>>>(y_pred, out);
}

// Round 8
// 255.270 us; speedup vs baseline: 1.1898x; 1.1898x over previous
//
#include <hip/hip_runtime.h>
#include <math.h>

#define DIM 192
#define OD  191          // output domain per axis (191^3 outputs)
#define PLN 36864        // 192^2
#define VOLX 7077888     // 192^3
#define TW 32            // 2 voxels per thread in w
#define TH 16
#define NBW 6            // ceil(191/32)
#define NBH 12           // ceil(191/16)
#define CD  8
#define NCH 24           // 24*8 = 192 >= 191

#define RH 19            // raw halo rows   (h0-1 .. h0+17)
#define RW 35            // raw halo cols   (w0-1 .. w0+33)
#define NS (RH*RW)       // 665 staging points
#define DH 18            // diff rows
#define DW 34            // diff cols
#define SBW 34           // sB row stride

typedef _Float16 h2v __attribute__((ext_vector_type(2)));
typedef _Float16 h4  __attribute__((ext_vector_type(4)));
typedef _Float16 h8  __attribute__((ext_vector_type(8)));
typedef unsigned int u2v __attribute__((ext_vector_type(2)));

static __device__ __forceinline__ h4 habs4(h4 v) {
    u2v u = __builtin_bit_cast(u2v, v);
    u &= 0x7FFF7FFFu;
    return __builtin_bit_cast(h4, u);
}

// Fused: diff -> 3x3x3 box mean -> neo-hookean energy -> mean reduction.
// LDS = 17.9 KB (ONE raw plane + single diff buffer) => 8 blocks/CU by LDS.
// Register-lean: 2-deep pending window sums, inline phase-b descriptors,
// launch_bounds(256,7) so the allocator has ~73 VGPRs (R7's (,8) forced 32
// and spilled 247 MB to scratch).
__global__ __launch_bounds__(256, 7)
void nh_fused_kernel(const float* __restrict__ P, float* __restrict__ out) {
    const int tid = threadIdx.x;
    const int tx = tid & 15, ty = tid >> 4;
    const int w0 = blockIdx.x * TW, h0 = blockIdx.y * TH;
    const int ds = blockIdx.z * CD;
    const int de = min(ds + CD, OD);
    const int lastP = min(de + 1, DIM - 1);   // last raw plane index needed

    __shared__ h4  sraw[RH][RW];      // raw f16 {c0,c1,c2,0}; ONE plane
    __shared__ h8  sA[DH][RW];        // {H0,H1,H2,W0, D0,D1,D2,W1}
    __shared__ h2v sB[DH][SBW];       // {W2,0}
    __shared__ float wsum[4];

    const int oh = h0 + ty, ow0 = w0 + 2 * tx;
    const bool v0 = (oh < OD) && (ow0 < OD);
    const bool v1 = (oh < OD) && (ow0 + 1 < OD);

    // ---- minimal hoisted staging descriptors (665 pts, <=3 per thread) ----
    int  sL[3], sOff[3];
    bool sAct[3], sMask[3];
    #pragma unroll
    for (int i = 0; i < 3; ++i) {
        int l = tid + 256 * i;
        sAct[i] = (l < NS);
        l = min(l, NS - 1);
        const int sh = l / RW, sw = l - sh * RW;
        const int hp = h0 - 1 + sh, wp = w0 - 1 + sw;
        sMask[i] = (hp >= 0) && (hp < DIM) && (wp >= 0) && (wp < DIM);
        sOff[i]  = min(max(hp, 0), DIM - 1) * DIM + min(max(wp, 0), DIM - 1);
        sL[i]    = l;
    }

    // in-flight prefetch registers (one raw plane, 3 channels, 3 items)
    float px[3][3];
    #pragma unroll
    for (int i = 0; i < 3; ++i) { px[i][0] = px[i][1] = px[i][2] = 0.f; }

    auto issue = [&](int q) {
        #pragma unroll
        for (int i = 0; i < 3; ++i) {
            if (sAct[i]) {
                const float* b = P + (size_t)q * PLN + sOff[i];
                px[i][0] = b[0]; px[i][1] = b[VOLX]; px[i][2] = b[2 * VOLX];
            }
        }
    };

    // ---- prologue: LDS raw <- plane ds-1 (if any); regs <- plane ds ----
    h4* const rawp = &sraw[0][0];
    if (ds >= 1) {
        issue(ds - 1);
        #pragma unroll
        for (int i = 0; i < 3; ++i) {
            if (sAct[i]) {
                rawp[sL[i]] = sMask[i] ? (h4){(_Float16)px[i][0], (_Float16)px[i][1],
                                              (_Float16)px[i][2], (_Float16)0.f}
                                       : (h4)0;
            }
        }
        issue(ds);
    } else {
        issue(0);   // loop's p=-1 iteration skips phase b; raw contents unread
    }
    __syncthreads();

    // 2-deep pending window sums per output: after iter p,
    //   pend0 = w(p-1)+w(p), pend1 = w(p)
    h8 pA0[2], pA1[2];
    h2v pBB[2];                       // {pend0, pend1} packed per output
    #pragma unroll
    for (int o = 0; o < 2; ++o) { pA0[o] = (h8)0; pA1[o] = (h8)0; pBB[o] = (h2v)0; }
    float acc = 0.f;

    for (int p = ds - 1; p <= de; ++p) {
        const bool pv = (p >= 0) && (p < OD);

        // convert prefetch regs (plane p+1) to f16 once; then px is free
        h4 cvt[3];
        #pragma unroll
        for (int i = 0; i < 3; ++i) {
            cvt[i] = sMask[i] ? (h4){(_Float16)px[i][0], (_Float16)px[i][1],
                                     (_Float16)px[i][2], (_Float16)0.f}
                              : (h4)0;
        }
        // launch next prefetch (plane p+2) — a full plane of compute ahead
        if (p + 2 <= lastP) issue(p + 2);

        // phase b: diffs of plane p (reads LDS raw plane p + cvt regs plane p+1)
        if (pv) {
            h8*  paA = &sA[0][0];
            h2v* paB = &sB[0][0];
            #pragma unroll
            for (int i = 0; i < 3; ++i) {
                const int l = sL[i];
                const int sh = l / RW, sw = l - sh * RW;     // recomputed (reg diet)
                if (sAct[i] && sh < DH && sw < DW) {
                    const h4 c  = rawp[l];
                    h4 hd = habs4(rawp[l + RW] - c);   // H-diff
                    h4 wd = habs4(rawp[l + 1]  - c);   // W-diff
                    h4 dd = habs4(cvt[i]       - c);   // D-diff (regs)
                    const int hp = h0 - 1 + sh, wp = w0 - 1 + sw;
                    if (hp < 0 || hp >= OD || wp < 0 || wp >= OD) {
                        hd = (h4)0; wd = (h4)0; dd = (h4)0;
                    }
                    const h4 lo = __builtin_shufflevector(hd, wd, 0, 1, 2, 4);
                    const h4 hi = __builtin_shufflevector(dd, wd, 0, 1, 2, 5);
                    paA[l] = __builtin_shufflevector(lo, hi, 0, 1, 2, 3, 4, 5, 6, 7);
                    paB[l - sh] = (h2v){wd[2], (_Float16)0.f};   // sh*34+sw = l-sh
                }
            }
        }
        __syncthreads();

        // phase c: 3x3 window sums w(p) for 2 outputs
        h8 wv[2]; _Float16 wb[2];
        if (pv) {
            h8 s0 = (h8)0, s1 = (h8)0;
            _Float16 q0 = (_Float16)0.f, q1 = (_Float16)0.f;
            #pragma unroll
            for (int j = 0; j < 3; ++j) {
                const h8* rowA = &sA[ty + j][2 * tx];
                const h8 t0 = rowA[0], t1 = rowA[1], t2 = rowA[2], t3 = rowA[3];
                const h4* rowB = (const h4*)&sB[ty + j][2 * tx];
                const h4 u01 = rowB[0], u23 = rowB[1];   // {W2(c),0,W2(c+1),0} x2
                const h8 m = t1 + t2;
                s0 += t0 + m;
                s1 += t3 + m;
                const _Float16 mB = u01[2] + u23[0];
                q0 += u01[0] + mB;
                q1 += u23[2] + mB;
            }
            wv[0] = s0; wv[1] = s1; wb[0] = q0; wb[1] = q1;
        } else {
            wv[0] = (h8)0; wv[1] = (h8)0;
            wb[0] = (_Float16)0.f; wb[1] = (_Float16)0.f;
        }

        // emit output plane d = p-1: F = pend0 + w(p); then rotate pendings
        const int d = p - 1;
        #pragma unroll
        for (int o = 0; o < 2; ++o) {
            if (d >= ds && (o == 0 ? v0 : v1)) {
                const h8 FA = pA0[o] + wv[o];
                const float FBz = (float)(pBB[o][0] + wb[o]);
                const float inv27 = 1.f / 27.f;
                const float dydx = (float)FA[0] * inv27, dxdx = (float)FA[1] * inv27, dzdx = (float)FA[2] * inv27;
                const float dydz = (float)FA[3] * inv27;                       // W0
                const float dydy = (float)FA[4] * inv27, dxdy = (float)FA[5] * inv27, dzdy = (float)FA[6] * inv27;
                const float dxdz = (float)FA[7] * inv27;                       // W1
                const float dzdz = FBz * inv27;                                 // W2
                const float a = dxdx + 1.f, e = dydy + 1.f, iN = dzdz + 1.f;
                const float J = a * (e * iN - dydz * dzdy)
                              - dxdy * (dydx * iN - dydz * dzdx)
                              + dxdz * (dydx * dzdy - e * dzdx);
                const float Tr = a * a + dxdy * dxdy + dxdz * dxdz
                               + dydx * dydx + e * e + dydz * dydz
                               + dzdx * dzdx + dzdy * dzdy + iN * iN;
                const float stretch = Tr * __expf(1.f - J) - 3.f;
                const float vol = (J - 1.f) * (J - 1.f);
                // mu=1,lam=5 -> U = (1/12)*stretch + (15/31)*vol (verified R1-R7)
                acc += 0.0833333358f * stretch + 0.4838709677f * vol;
            }
            pA0[o] = pA1[o] + wv[o];
            pA1[o] = wv[o];
            pBB[o] = (h2v){pBB[o][1] + wb[o], wb[o]};
        }

        // raw update: LDS raw <- plane p+1 (phase-b readers done at barrier)
        #pragma unroll
        for (int i = 0; i < 3; ++i) {
            if (sAct[i]) rawp[sL[i]] = cvt[i];
        }
        __syncthreads();
    }

    // mean scaling (191^3)
    acc *= (1.f / 6967871.f);

    // wave reduce (64 lanes), then block reduce, one atomic per block
    #pragma unroll
    for (int off = 32; off > 0; off >>= 1) acc += __shfl_down(acc, off, 64);
    if ((tid & 63) == 0) wsum[tid >> 6] = acc;
    __syncthreads();
    if (tid == 0) {
        atomicAdd(out, wsum[0] + wsum[1] + wsum[2] + wsum[3]);
    }
}

extern "C" void kernel_launch(void* const* d_in, const int* in_sizes, int n_in,
                              void* d_out, int out_size, void* d_ws, size_t ws_size,
                              hipStream_t stream) {
    const float* y_pred = (const float*)d_in[0];
    float* out = (float*)d_out;

    // d_out is poisoned 0xAA before every timed launch — zero it (graph-capturable).
    hipMemsetAsync(out, 0, sizeof(float), stream);

    dim3 grid(NBW, NBH, NCH);
    nh_fused_kernel<<<grid, 256, 0, stream>>>(y_pred, out);
}